// Round 1
// baseline (544.326 us; speedup 1.0000x reference)
//
#include <hip/hip_runtime.h>

#define C 128
#define NBLK 2048
#define NITER 10

// v[j] = 1.0 initializer (ws is poisoned 0xAA; must init every call)
__global__ __launch_bounds__(128)
void init_v_kernel(float* __restrict__ v) {
    if (threadIdx.x < C) v[threadIdx.x] = 1.0f;
}

// One Sinkhorn iteration pass over S:
//   u_i      = 1 / sum_j exp(S_ij) * v_j
//   partial[blk][j] = sum over this block's rows of exp(S_ij) * u_i
// Each 32-lane half-wave owns one row; lane l (0..31) holds columns 4l..4l+3.
__global__ __launch_bounds__(256)
void sink_pass(const float* __restrict__ S, const float* __restrict__ v,
               float* __restrict__ u, float* __restrict__ partial,
               int N, int write_u) {
    const int tid = threadIdx.x;
    const int l = tid & 31;                       // lane within half-wave
    const int hw_in_block = tid >> 5;             // 0..7
    const int ghw = blockIdx.x * (blockDim.x >> 5) + hw_in_block;
    const int nhw = gridDim.x * (blockDim.x >> 5);

    const float4 vv = reinterpret_cast<const float4*>(v)[l];

    float a0 = 0.f, a1 = 0.f, a2 = 0.f, a3 = 0.f;

    for (int i = ghw; i < N; i += nhw) {
        const float4 s4 = reinterpret_cast<const float4*>(S)[(size_t)i * 32 + l];
        const float e0 = __expf(s4.x);
        const float e1 = __expf(s4.y);
        const float e2 = __expf(s4.z);
        const float e3 = __expf(s4.w);
        float p = e0 * vv.x + e1 * vv.y + e2 * vv.z + e3 * vv.w;
        // reduce across the 32-lane half (xor<32 stays within each half of wave64)
        p += __shfl_xor(p, 16);
        p += __shfl_xor(p, 8);
        p += __shfl_xor(p, 4);
        p += __shfl_xor(p, 2);
        p += __shfl_xor(p, 1);
        const float ui = 1.0f / p;
        if (write_u && l == 0) u[i] = ui;
        a0 += e0 * ui;
        a1 += e1 * ui;
        a2 += e2 * ui;
        a3 += e3 * ui;
    }

    // block-reduce the per-lane column accumulators (8 half-waves)
    __shared__ float sh[8][C];
    sh[hw_in_block][4 * l + 0] = a0;
    sh[hw_in_block][4 * l + 1] = a1;
    sh[hw_in_block][4 * l + 2] = a2;
    sh[hw_in_block][4 * l + 3] = a3;
    __syncthreads();
    if (tid < C) {
        float s = 0.f;
        #pragma unroll
        for (int w = 0; w < 8; ++w) s += sh[w][tid];
        partial[(size_t)blockIdx.x * C + tid] = s;
    }
}

// v[j] = ratios[j] * total_num / sum_k partial[k][j]   (one block per column)
__global__ __launch_bounds__(256)
void vupdate(const float* __restrict__ partial, const float* __restrict__ ratios,
             const int* __restrict__ tn, float* __restrict__ v, int nblk) {
    const int j = blockIdx.x;
    const int tid = threadIdx.x;
    float s = 0.f;
    for (int k = tid; k < nblk; k += 256)
        s += partial[(size_t)k * C + j];
    #pragma unroll
    for (int off = 32; off; off >>= 1) s += __shfl_xor(s, off);
    __shared__ float sh[4];
    if ((tid & 63) == 0) sh[tid >> 6] = s;
    __syncthreads();
    if (tid == 0) {
        const float t = sh[0] + sh[1] + sh[2] + sh[3];
        v[j] = ratios[j] * (float)(*tn) / t;
    }
}

// P_ij = exp(S_ij) * u_i * v_j
__global__ __launch_bounds__(256)
void output_kernel(const float* __restrict__ S, const float* __restrict__ u,
                   const float* __restrict__ v, float* __restrict__ out, int N) {
    const size_t total4 = (size_t)N * 32;  // float4 count (C/4 = 32 per row)
    const size_t stride = (size_t)gridDim.x * blockDim.x;
    for (size_t idx = (size_t)blockIdx.x * blockDim.x + threadIdx.x;
         idx < total4; idx += stride) {
        const size_t row = idx >> 5;
        const int c4 = (int)(idx & 31);
        const float4 s4 = reinterpret_cast<const float4*>(S)[idx];
        const float ui = u[row];
        const float4 v4 = reinterpret_cast<const float4*>(v)[c4];
        float4 o;
        o.x = __expf(s4.x) * ui * v4.x;
        o.y = __expf(s4.y) * ui * v4.y;
        o.z = __expf(s4.z) * ui * v4.z;
        o.w = __expf(s4.w) * ui * v4.w;
        reinterpret_cast<float4*>(out)[idx] = o;
    }
}

extern "C" void kernel_launch(void* const* d_in, const int* in_sizes, int n_in,
                              void* d_out, int out_size, void* d_ws, size_t ws_size,
                              hipStream_t stream) {
    // inputs: 0 features, 1 text_features, 2 sim_matrix_whole, 3 ratios, 4 targets, 5 total_num
    const float* S      = (const float*)d_in[2];
    const float* ratios = (const float*)d_in[3];
    const int*   tn     = (const int*)d_in[5];
    const int N = in_sizes[2] / C;   // 500000
    float* out = (float*)d_out;

    char* ws = (char*)d_ws;
    float* u = (float*)ws;                                   // N floats
    size_t off = (((size_t)N * 4) + 255) & ~(size_t)255;
    float* v = (float*)(ws + off);                           // C floats (16B aligned)
    float* partial = (float*)(ws + off + 512);               // NBLK*C floats

    init_v_kernel<<<1, 128, 0, stream>>>(v);
    for (int it = 0; it < NITER; ++it) {
        sink_pass<<<NBLK, 256, 0, stream>>>(S, v, u, partial, N, it == NITER - 1);
        vupdate<<<C, 256, 0, stream>>>(partial, ratios, tn, v, NBLK);
    }
    output_kernel<<<2048, 256, 0, stream>>>(S, u, v, out, N);
}

// Round 2
// 391.386 us; speedup vs baseline: 1.3908x; 1.3908x over previous
//
#include <hip/hip_runtime.h>
#include <hip/hip_fp16.h>

#define C 128
#define NBLK 2048
#define NITER 10

// ---------------- shared small kernels ----------------

__global__ __launch_bounds__(128)
void init_v_kernel(float* __restrict__ v) {
    if (threadIdx.x < C) v[threadIdx.x] = 1.0f;
}

// v[j] = ratios[j] * total_num / sum_k partial[k][j]   (one block per column)
__global__ __launch_bounds__(256)
void vupdate(const float* __restrict__ partial, const float* __restrict__ ratios,
             const int* __restrict__ tn, float* __restrict__ v, int nblk) {
    const int j = blockIdx.x;
    const int tid = threadIdx.x;
    float s = 0.f;
    for (int k = tid; k < nblk; k += 256)
        s += partial[(size_t)k * C + j];
    #pragma unroll
    for (int off = 32; off; off >>= 1) s += __shfl_xor(s, off);
    __shared__ float sh[4];
    if ((tid & 63) == 0) sh[tid >> 6] = s;
    __syncthreads();
    if (tid == 0) {
        const float t = sh[0] + sh[1] + sh[2] + sh[3];
        v[j] = ratios[j] * (float)(*tn) / t;
    }
}

// ---------------- fp16-E fast path ----------------

// Pass 1: read f32 S, E=exp(S) stored fp16; iteration 1 with v=1:
//   u_i = 1/sum_j e_ij ; partial[blk][j] = sum_rows e_ij*u_i
// 32 lanes per row, 4 cols per lane.
__global__ __launch_bounds__(256)
void sink_first(const float* __restrict__ S, __half* __restrict__ E,
                float* __restrict__ partial, int N) {
    const int tid = threadIdx.x;
    const int l = tid & 31;
    const int hw = tid >> 5;
    const int ghw = blockIdx.x * 8 + hw;
    const int nhw = gridDim.x * 8;

    float a0 = 0.f, a1 = 0.f, a2 = 0.f, a3 = 0.f;

    for (int i = ghw; i < N; i += nhw) {
        const float4 s4 = reinterpret_cast<const float4*>(S)[(size_t)i * 32 + l];
        const float e0 = __expf(s4.x);
        const float e1 = __expf(s4.y);
        const float e2 = __expf(s4.z);
        const float e3 = __expf(s4.w);
        union { __half2 h2[2]; uint2 u2; } pk;
        pk.h2[0] = __floats2half2_rn(e0, e1);
        pk.h2[1] = __floats2half2_rn(e2, e3);
        reinterpret_cast<uint2*>(E)[(size_t)i * 32 + l] = pk.u2;
        float p = e0 + e1 + e2 + e3;
        p += __shfl_xor(p, 16);
        p += __shfl_xor(p, 8);
        p += __shfl_xor(p, 4);
        p += __shfl_xor(p, 2);
        p += __shfl_xor(p, 1);
        const float ui = 1.0f / p;
        a0 += e0 * ui;
        a1 += e1 * ui;
        a2 += e2 * ui;
        a3 += e3 * ui;
    }

    __shared__ float sh[8][C];
    sh[hw][4 * l + 0] = a0;
    sh[hw][4 * l + 1] = a1;
    sh[hw][4 * l + 2] = a2;
    sh[hw][4 * l + 3] = a3;
    __syncthreads();
    if (tid < C) {
        float s = 0.f;
        #pragma unroll
        for (int w = 0; w < 8; ++w) s += sh[w][tid];
        partial[(size_t)blockIdx.x * C + tid] = s;
    }
}

// Iteration pass on fp16 E. 16 lanes per row, 8 cols per lane (16B loads).
__global__ __launch_bounds__(256)
void sink_pass_h(const __half* __restrict__ E, const float* __restrict__ v,
                 float* __restrict__ u, float* __restrict__ partial,
                 int N, int write_u) {
    const int tid = threadIdx.x;
    const int l = tid & 15;           // cols 8l..8l+7
    const int g = tid >> 4;           // 16 groups per block
    const int ggr = blockIdx.x * 16 + g;
    const int ngr = gridDim.x * 16;

    const float4 va = reinterpret_cast<const float4*>(v)[2 * l];
    const float4 vb = reinterpret_cast<const float4*>(v)[2 * l + 1];

    float a[8] = {0.f, 0.f, 0.f, 0.f, 0.f, 0.f, 0.f, 0.f};

    for (int i = ggr; i < N; i += ngr) {
        union { uint4 q; __half2 h2[4]; } pk;
        pk.q = reinterpret_cast<const uint4*>(E)[(size_t)i * 16 + l];
        const float2 f0 = __half22float2(pk.h2[0]);
        const float2 f1 = __half22float2(pk.h2[1]);
        const float2 f2 = __half22float2(pk.h2[2]);
        const float2 f3 = __half22float2(pk.h2[3]);
        float e[8] = {f0.x, f0.y, f1.x, f1.y, f2.x, f2.y, f3.x, f3.y};
        float p = e[0] * va.x + e[1] * va.y + e[2] * va.z + e[3] * va.w
                + e[4] * vb.x + e[5] * vb.y + e[6] * vb.z + e[7] * vb.w;
        p += __shfl_xor(p, 8);
        p += __shfl_xor(p, 4);
        p += __shfl_xor(p, 2);
        p += __shfl_xor(p, 1);
        const float ui = 1.0f / p;
        if (write_u && l == 0) u[i] = ui;
        #pragma unroll
        for (int k = 0; k < 8; ++k) a[k] += e[k] * ui;
    }

    __shared__ float sh[16][C];
    #pragma unroll
    for (int k = 0; k < 8; ++k) sh[g][8 * l + k] = a[k];
    __syncthreads();
    if (tid < C) {
        float s = 0.f;
        #pragma unroll
        for (int w = 0; w < 16; ++w) s += sh[w][tid];
        partial[(size_t)blockIdx.x * C + tid] = s;
    }
}

// P_ij = E_h[i][j] * u_i * v_j  (8 cols per thread)
__global__ __launch_bounds__(256)
void output_h(const __half* __restrict__ E, const float* __restrict__ u,
              const float* __restrict__ v, float* __restrict__ out, int N) {
    const size_t total = (size_t)N * 16;
    const size_t stride = (size_t)gridDim.x * blockDim.x;
    for (size_t idx = (size_t)blockIdx.x * blockDim.x + threadIdx.x;
         idx < total; idx += stride) {
        const size_t row = idx >> 4;
        const int c8 = (int)(idx & 15);
        union { uint4 q; __half2 h2[4]; } pk;
        pk.q = reinterpret_cast<const uint4*>(E)[idx];
        const float ui = u[row];
        const float4 va = reinterpret_cast<const float4*>(v)[2 * c8];
        const float4 vb = reinterpret_cast<const float4*>(v)[2 * c8 + 1];
        const float2 f0 = __half22float2(pk.h2[0]);
        const float2 f1 = __half22float2(pk.h2[1]);
        const float2 f2 = __half22float2(pk.h2[2]);
        const float2 f3 = __half22float2(pk.h2[3]);
        float4 o0, o1;
        o0.x = f0.x * ui * va.x;  o0.y = f0.y * ui * va.y;
        o0.z = f1.x * ui * va.z;  o0.w = f1.y * ui * va.w;
        o1.x = f2.x * ui * vb.x;  o1.y = f2.y * ui * vb.y;
        o1.z = f3.x * ui * vb.z;  o1.w = f3.y * ui * vb.w;
        reinterpret_cast<float4*>(out)[2 * idx]     = o0;
        reinterpret_cast<float4*>(out)[2 * idx + 1] = o1;
    }
}

// ---------------- f32 fallback path (round-1 proven) ----------------

__global__ __launch_bounds__(256)
void sink_pass(const float* __restrict__ S, const float* __restrict__ v,
               float* __restrict__ u, float* __restrict__ partial,
               int N, int write_u) {
    const int tid = threadIdx.x;
    const int l = tid & 31;
    const int hw = tid >> 5;
    const int ghw = blockIdx.x * 8 + hw;
    const int nhw = gridDim.x * 8;

    const float4 vv = reinterpret_cast<const float4*>(v)[l];
    float a0 = 0.f, a1 = 0.f, a2 = 0.f, a3 = 0.f;

    for (int i = ghw; i < N; i += nhw) {
        const float4 s4 = reinterpret_cast<const float4*>(S)[(size_t)i * 32 + l];
        const float e0 = __expf(s4.x);
        const float e1 = __expf(s4.y);
        const float e2 = __expf(s4.z);
        const float e3 = __expf(s4.w);
        float p = e0 * vv.x + e1 * vv.y + e2 * vv.z + e3 * vv.w;
        p += __shfl_xor(p, 16);
        p += __shfl_xor(p, 8);
        p += __shfl_xor(p, 4);
        p += __shfl_xor(p, 2);
        p += __shfl_xor(p, 1);
        const float ui = 1.0f / p;
        if (write_u && l == 0) u[i] = ui;
        a0 += e0 * ui;
        a1 += e1 * ui;
        a2 += e2 * ui;
        a3 += e3 * ui;
    }

    __shared__ float sh[8][C];
    sh[hw][4 * l + 0] = a0;
    sh[hw][4 * l + 1] = a1;
    sh[hw][4 * l + 2] = a2;
    sh[hw][4 * l + 3] = a3;
    __syncthreads();
    if (tid < C) {
        float s = 0.f;
        #pragma unroll
        for (int w = 0; w < 8; ++w) s += sh[w][tid];
        partial[(size_t)blockIdx.x * C + tid] = s;
    }
}

__global__ __launch_bounds__(256)
void output_kernel(const float* __restrict__ S, const float* __restrict__ u,
                   const float* __restrict__ v, float* __restrict__ out, int N) {
    const size_t total4 = (size_t)N * 32;
    const size_t stride = (size_t)gridDim.x * blockDim.x;
    for (size_t idx = (size_t)blockIdx.x * blockDim.x + threadIdx.x;
         idx < total4; idx += stride) {
        const size_t row = idx >> 5;
        const int c4 = (int)(idx & 31);
        const float4 s4 = reinterpret_cast<const float4*>(S)[idx];
        const float ui = u[row];
        const float4 v4 = reinterpret_cast<const float4*>(v)[c4];
        float4 o;
        o.x = __expf(s4.x) * ui * v4.x;
        o.y = __expf(s4.y) * ui * v4.y;
        o.z = __expf(s4.z) * ui * v4.z;
        o.w = __expf(s4.w) * ui * v4.w;
        reinterpret_cast<float4*>(out)[idx] = o;
    }
}

// ---------------- launch ----------------

extern "C" void kernel_launch(void* const* d_in, const int* in_sizes, int n_in,
                              void* d_out, int out_size, void* d_ws, size_t ws_size,
                              hipStream_t stream) {
    const float* S      = (const float*)d_in[2];
    const float* ratios = (const float*)d_in[3];
    const int*   tn     = (const int*)d_in[5];
    const int N = in_sizes[2] / C;   // 500000
    float* out = (float*)d_out;

    char* ws = (char*)d_ws;
    size_t off = 0;
    float* u = (float*)(ws + off);          off += (((size_t)N * 4) + 255) & ~(size_t)255;
    float* v = (float*)(ws + off);          off += 512;
    float* partial = (float*)(ws + off);    off += (size_t)NBLK * C * 4;
    off = (off + 255) & ~(size_t)255;
    __half* E = (__half*)(ws + off);
    const size_t need = off + (size_t)N * C * 2;

    if (ws_size >= need) {
        // fp16-E fast path
        sink_first<<<NBLK, 256, 0, stream>>>(S, E, partial, N);
        vupdate<<<C, 256, 0, stream>>>(partial, ratios, tn, v, NBLK);
        for (int it = 1; it < NITER; ++it) {
            sink_pass_h<<<NBLK, 256, 0, stream>>>(E, v, u, partial, N, it == NITER - 1);
            vupdate<<<C, 256, 0, stream>>>(partial, ratios, tn, v, NBLK);
        }
        output_h<<<2048, 256, 0, stream>>>(E, u, v, out, N);
    } else {
        // f32 fallback
        init_v_kernel<<<1, 128, 0, stream>>>(v);
        for (int it = 0; it < NITER; ++it) {
            sink_pass<<<NBLK, 256, 0, stream>>>(S, v, u, partial, N, it == NITER - 1);
            vupdate<<<C, 256, 0, stream>>>(partial, ratios, tn, v, NBLK);
        }
        output_kernel<<<2048, 256, 0, stream>>>(S, u, v, out, N);
    }
}